// Round 18
// baseline (689.048 us; speedup 1.0000x reference)
//
#include <hip/hip_runtime.h>
#include <hip/hip_bf16.h>
#include <math.h>

// Problem constants
constexpr int Bn = 2048, Mm = 2, Vv = 25, Dd = 64;
constexpr int C1 = 128, C2 = 256, Kk = 3, Uu = 256;
constexpr int NJ = Mm*Vv*Uu;     // 12800
constexpr int NBd = Mm*Uu;       // 512
constexpr int SD = NJ+NBd+Uu;    // 13568
constexpr int Nn = Bn*Mm;        // 4096
constexpr int N3 = Nn*Vv;        // 102400
constexpr int NCH = 2;
constexpr int NnC = Nn/NCH;      // 2048
constexpr int RCn = NnC*Vv;      // 51200 rows per chunk

typedef __bf16 v8bf __attribute__((ext_vector_type(8)));
typedef float f32x16 __attribute__((ext_vector_type(16)));

__device__ __forceinline__ float hsig(float z){ return fminf(fmaxf(0.2f*z+0.5f,0.f),1.f); }
__device__ __forceinline__ float ftanh(float x){
  float e = __expf(2.f*x);
  return 1.f - 2.f*__frcp_rn(e+1.f);
}
__device__ __forceinline__ unsigned short f2bs(float x){
  __hip_bfloat16 h = __float2bfloat16(x);
  unsigned short s; __builtin_memcpy(&s, &h, 2); return s;
}
__device__ __forceinline__ float bs2f(unsigned short s){
  unsigned u = ((unsigned)s)<<16; float f; __builtin_memcpy(&f,&u,4); return f;
}

// Async global->LDS 16B: dst_base is the wave-uniform frag base; HW writes
// base + lane*16.
#if defined(__has_builtin)
#if __has_builtin(__builtin_amdgcn_global_load_lds)
#define HAS_ALD 1
#endif
#endif
#ifndef HAS_ALD
#define HAS_ALD 0
#endif
__device__ __forceinline__ void stage16(unsigned short* dst_base, int lane, const void* src){
#if HAS_ALD
  __builtin_amdgcn_global_load_lds(
      (const __attribute__((address_space(1))) unsigned int*)src,
      (__attribute__((address_space(3))) unsigned int*)dst_base, 16, 0, 0);
#else
  *(uint4*)(dst_base + lane*8) = *(const uint4*)src;
#endif
}

// ---------------------------------------------------------------------------
// kMix<SW,TI>: v-mixing by adjacency (unchanged, verified)
// ---------------------------------------------------------------------------
template<int SW, typename TI>
__global__ __launch_bounds__(SW*3) void kMix(
    const TI* __restrict__ src, const float* __restrict__ Amat,
    const float* __restrict__ ei, int eoff, unsigned short* __restrict__ dst)
{
  __shared__ float xs[Vv*SW];
  __shared__ float as[Kk*Vv*Vv];
  const int n = blockIdx.x, t = threadIdx.x;
  const TI* srow = src + (size_t)n*(Vv*SW);
  for(int i=t;i<Vv*SW;i+=SW*3){
    if constexpr (sizeof(TI)==2) xs[i]=bs2f((unsigned short)srow[i]);
    else xs[i]=srow[i];
  }
  for(int i=t;i<Kk*Vv*Vv;i+=SW*3) as[i]=ei[eoff+i]*Amat[i];
  __syncthreads();
  const int k = t/SW, d = t%SW;
  float acc[Vv];
  #pragma unroll
  for(int w=0;w<Vv;++w) acc[w]=0.f;
  for(int v=0;v<Vv;++v){
    float xv = xs[v*SW+d];
    const float* ap = &as[k*625 + v*25];
    #pragma unroll
    for(int w=0;w<Vv;++w) acc[w] += ap[w]*xv;
  }
  unsigned short* drow = dst + (size_t)n*(Vv*3*SW);
  for(int w=0;w<Vv;++w) drow[w*(3*SW) + t] = f2bs(acc[w]);
}

// ---------------------------------------------------------------------------
// hoffOf: MODE 0 joint, 1 body, 2 whole
// ---------------------------------------------------------------------------
template<int MODE>
__device__ __forceinline__ size_t hoffOf(int row){
  if constexpr (MODE==0){ int b=row/50, j=row-b*50; return (size_t)b*SD + j*256; }
  else if constexpr (MODE==1){ int b=row>>1, m=row&1; return (size_t)b*SD + NJ + m*256; }
  else return (size_t)row*SD + NJ + NBd;
}

// ---------------------------------------------------------------------------
// kConvW<MODE>: weights fp32 -> bf16 in MFMA FRAGMENT order (unchanged).
// ---------------------------------------------------------------------------
template<int MODE>
__global__ __launch_bounds__(256) void kConvW(
    const float* __restrict__ Wm, const float* __restrict__ Wr,
    unsigned short* __restrict__ out, int total)
{
  int i = blockIdx.x*256 + threadIdx.x;
  if(i>=total) return;
  int e = i&7, ln = (i>>3)&63, l31 = ln&31, l5 = ln>>5;
  float v;
  if constexpr (MODE<=2){
    constexpr int KF = (MODE==0)?256:(MODE==1)?6400:12800;
    constexpr int NKT = (KF+256)/32;
    int fb = (i>>9)&15, kt = (i>>13)%NKT, ublk = i/(NKT*8192);
    int kh = fb&1, cg = fb>>1;
    int k = kt*32 + l5*8 + kh*16 + e;
    int g = cg&3, uu = (cg>>2)*32 + l31;
    int col = g*256 + ublk*64 + uu;
    v = (k<KF) ? Wm[(size_t)k*1024+col] : Wr[(size_t)(k-KF)*1024+col];
  } else if constexpr (MODE==3){
    int fb = (i>>9)&15, kt = i>>13;
    int kh = fb&1, cg = fb>>1;
    int k = kt*32 + l5*8 + kh*16 + e;
    int col = cg*32 + l31;
    v = (k<384) ? Wm[(size_t)(k&127)*768 + (k>>7)*256 + col]
                : Wr[(size_t)(k-384)*256 + col];
  } else {
    int fb = (i>>9)&7, kt = i>>12;
    int kh = fb&1, cg = fb>>1;
    int k = kt*32 + l5*8 + kh*16 + e;
    int col = cg*32 + l31;
    v = Wm[(size_t)(k&63)*384 + (k>>6)*128 + col];
  }
  out[i] = f2bs(v);
}

// ---------------------------------------------------------------------------
// kConvH<MODE>: h0 fp32 -> bf16, row-major [rows][256] in GEMM row order.
// ---------------------------------------------------------------------------
template<int MODE>
__global__ __launch_bounds__(256) void kConvH(
    const float* __restrict__ h0, unsigned short* __restrict__ dst, int total4)
{
  int i = blockIdx.x*256 + threadIdx.x;
  if(i>=total4) return;
  int row = i>>6, k4 = (i&63)*4;
  const float* s = h0 + hoffOf<MODE>(row) + k4;
  float4 f = *(const float4*)s;
  uint2 o;
  o.x = (unsigned)f2bs(f.x) | ((unsigned)f2bs(f.y)<<16);
  o.y = (unsigned)f2bs(f.z) | ((unsigned)f2bs(f.w)<<16);
  *(uint2*)(dst + (size_t)i*4) = o;
}

// ---------------------------------------------------------------------------
// kLSTMm<MODE,WT>: MFMA bf16 GEMM, block tile 128 rows x 256 staged cols,
// 8 waves (512 thr), counted-vmcnt 3-buffer pipeline (72 KB LDS, 2 blk/CU).
// WT=0: wave tile 32x128 (fused LSTM epilogue).  WT=1: 64x64 (partials).
// T5: s_setprio(1) around the MFMA cluster — the counted-vmcnt schedule has
// wave role-diversity (load-issuing vs MFMA waves), the regime where T5 pays.
// [r13: bound (512,2) only; r16: NRG=2 LDS/occ tradeoff loses]
// ---------------------------------------------------------------------------
template<int MODE, int WT>
__global__ __launch_bounds__(512,2) void kLSTMm(
    const unsigned short* __restrict__ featb, const unsigned short* __restrict__ h0b,
    const float* __restrict__ c0, const unsigned short* __restrict__ Wcat,
    const float* __restrict__ bias, float* __restrict__ outp, int KC)
{
  constexpr int KF = (MODE==0)?256:(MODE==1)?6400:12800;
  constexpr int KT = KF+256;
  constexpr int NKT = KT/32;
  constexpr int ROWS = (MODE==0)?N3:(MODE==1)?Nn:Bn;
  __shared__ unsigned short Afr[3][8*512];    // 8 KB x3
  __shared__ unsigned short Bfr[3][16*512];   // 16 KB x3  -> 72 KB total
  const int t = threadIdx.x;
  const int bx = blockIdx.x;
  const int r0 = (bx>>2)*128;
  const int ublk = bx&3;
  const int z = (MODE==0)?0:blockIdx.y;
  const int kBeg = z*KC, kEnd = min(KT, kBeg+KC);
  const int lane = t&63, wid = t>>6;          // wid in 0..7
  const int l31 = lane&31, l5 = lane>>5;
  // WT=0 partition
  const int wr = wid>>1, w2 = wid&1;
  // WT=1 partition
  const int wrr = wid>>2, wcc = wid&3;

  constexpr int AC = (WT==0)?4:2;
  constexpr int ARr = (WT==0)?1:2;
  f32x16 acc[ARr][AC];
  #pragma unroll
  for(int i=0;i<ARr;++i)
    #pragma unroll
    for(int j=0;j<AC;++j)
      #pragma unroll
      for(int e=0;e<16;++e) acc[i][j][e]=0.f;

  auto stageA = [&](unsigned short* dstb, int k0){
    int row = r0 + (wid>>1)*32 + l31;
    int kg = k0 + ((wid&1)*2 + l5)*8;
    const unsigned short* src = (kg < KF)
        ? featb + (size_t)row*KF + kg
        : h0b   + (size_t)row*256 + (kg - KF);
    stage16(dstb + (size_t)(wid*64)*8, lane, src);
  };
  auto stageB = [&](unsigned short* dstb, int k0){
    const unsigned short* wt = Wcat + ((size_t)ublk*NKT + (k0>>5))*8192;
    #pragma unroll
    for(int i=0;i<2;++i){
      int off = i*512 + wid*64;
      stage16(dstb + (size_t)off*8, lane, wt + (size_t)(off + lane)*8);
    }
  };
  auto mstep = [&](const unsigned short* Ab, const unsigned short* Bb){
    __builtin_amdgcn_s_setprio(1);
    if constexpr (WT==0){
      #pragma unroll
      for(int kh=0; kh<2; ++kh){
        v8bf a = *(const v8bf*)&Ab[(wr*2+kh)*512 + lane*8];
        #pragma unroll
        for(int g=0; g<4; ++g){
          v8bf b = *(const v8bf*)&Bb[((w2*4+g)*2+kh)*512 + lane*8];
          acc[0][g] = __builtin_amdgcn_mfma_f32_32x32x16_bf16(a, b, acc[0][g], 0, 0, 0);
        }
      }
    } else {
      #pragma unroll
      for(int kh=0; kh<2; ++kh){
        v8bf a[2], b[2];
        #pragma unroll
        for(int rq=0;rq<2;++rq)
          a[rq] = *(const v8bf*)&Ab[((wrr*2+rq)*2+kh)*512 + lane*8];
        #pragma unroll
        for(int cq=0;cq<2;++cq)
          b[cq] = *(const v8bf*)&Bb[((wcc*2+cq)*2+kh)*512 + lane*8];
        #pragma unroll
        for(int rq=0;rq<2;++rq)
          #pragma unroll
          for(int cq=0;cq<2;++cq)
            acc[rq][cq] = __builtin_amdgcn_mfma_f32_32x32x16_bf16(a[rq], b[cq], acc[rq][cq], 0, 0, 0);
      }
    }
    __builtin_amdgcn_s_setprio(0);
  };

  unsigned short *A0=&Afr[0][0], *A1=&Afr[1][0], *A2=&Afr[2][0];
  unsigned short *B0=&Bfr[0][0], *B1=&Bfr[1][0], *B2=&Bfr[2][0];
  const int nst = (kEnd-kBeg)>>5;
  stageA(A0, kBeg);    stageB(B0, kBeg);      // 3 loads
  stageA(A1, kBeg+32); stageB(B1, kBeg+32);   // 3 loads
  for(int s=0; s<nst-1; ++s){
    asm volatile("s_waitcnt vmcnt(3)" ::: "memory");   // stage(s) landed
    __builtin_amdgcn_s_barrier();
    if(s+2<nst){ stageA(A2, kBeg+(s+2)*32); stageB(B2, kBeg+(s+2)*32); }
    mstep(A0, B0);
    unsigned short* ta=A0; A0=A1; A1=A2; A2=ta;
    unsigned short* tb=B0; B0=B1; B1=B2; B2=tb;
  }
  asm volatile("s_waitcnt vmcnt(0)" ::: "memory");
  __builtin_amdgcn_s_barrier();
  mstep(A0, B0);

  if constexpr (MODE==0){
    const int u = ublk*64 + w2*32 + l31;
    #pragma unroll
    for(int reg=0; reg<16; ++reg){
      int row = r0 + wr*32 + (reg&3) + 8*(reg>>2) + 4*l5;
      int b = row/50, j = row - b*50;
      size_t hoff = (size_t)b*SD + j*256;
      int boff = j*1024;
      float zi = acc[0][0][reg] + bias[boff + u];
      float zf = acc[0][1][reg] + bias[boff + 256 + u];
      float zg = acc[0][2][reg] + bias[boff + 512 + u];
      float zo = acc[0][3][reg] + bias[boff + 768 + u];
      float iv=hsig(zi), fv=hsig(zf), gv=ftanh(zg), ov=hsig(zo);
      float cc = c0[hoff+u];
      float c2 = fv*cc + iv*gv;
      outp[hoff+u] = ov*ftanh(c2);
    }
  } else {
    // WT=1 partial store: lane owns cgs {wcc*2, wcc*2+1}; cg=(uu>>5)*4+g
    #pragma unroll
    for(int rq=0;rq<2;++rq){
      #pragma unroll
      for(int cq=0;cq<2;++cq){
        int cg = wcc*2+cq, g = cg&3, uh = cg>>2;
        int u = ublk*64 + uh*32 + l31;
        #pragma unroll
        for(int reg=0; reg<16; ++reg){
          int row = r0 + (wrr*2+rq)*32 + (reg&3) + 8*(reg>>2) + 4*l5;
          outp[((size_t)z*ROWS + row)*1024 + g*256 + u] = acc[rq][cq][reg];
        }
      }
    }
  }
}

// ---------------------------------------------------------------------------
// kGC2: graph GEMM2, 128x256 tile, 8 waves, counted-vmcnt pipeline + T5.
// ---------------------------------------------------------------------------
__global__ __launch_bounds__(512,2) void kGC2(
    const unsigned short* __restrict__ ycat, const unsigned short* __restrict__ yb,
    const unsigned short* __restrict__ Wc2, const float* __restrict__ bg1,
    const float* __restrict__ br1, const float* __restrict__ Amat,
    const float* __restrict__ ei, unsigned short* __restrict__ featb)
{
  __shared__ unsigned short Afr[3][8*512];
  __shared__ unsigned short Bfr[3][16*512];
  __shared__ float asums[75];
  const int t = threadIdx.x;
  const int r0 = blockIdx.x*128;
  if(t<75){
    int k=t/25, w=t%25; float s=0.f;
    for(int v=0;v<25;++v) s += ei[1875 + k*625+v*25+w]*Amat[k*625+v*25+w];
    asums[t]=s;
  }
  const int lane = t&63, wid = t>>6;
  const int wr = wid>>1, w2 = wid&1;
  const int l31 = lane&31, l5 = lane>>5;
  f32x16 acc[4];
  #pragma unroll
  for(int g=0;g<4;++g)
    #pragma unroll
    for(int j=0;j<16;++j) acc[g][j]=0.f;

  auto stageA = [&](unsigned short* dst, int k0){
    int row = r0 + (wid>>1)*32 + l31;
    int kg = k0 + ((wid&1)*2 + l5)*8;
    const unsigned short* src = (kg<384) ? ycat + (size_t)row*384 + kg
                                         : yb   + (size_t)row*128 + (kg-384);
    stage16(dst + (size_t)(wid*64)*8, lane, src);
  };
  auto stageB = [&](unsigned short* dst, int k0){
    const unsigned short* wt = Wc2 + (size_t)(k0>>5)*8192;
    #pragma unroll
    for(int i=0;i<2;++i){
      int off = i*512 + wid*64;
      stage16(dst + (size_t)off*8, lane, wt + (size_t)(off + lane)*8);
    }
  };
  auto mstep = [&](const unsigned short* Ab, const unsigned short* Bb){
    __builtin_amdgcn_s_setprio(1);
    #pragma unroll
    for(int kh=0; kh<2; ++kh){
      v8bf a = *(const v8bf*)&Ab[(wr*2+kh)*512 + lane*8];
      #pragma unroll
      for(int g=0; g<4; ++g){
        v8bf b = *(const v8bf*)&Bb[((w2*4+g)*2+kh)*512 + lane*8];
        acc[g] = __builtin_amdgcn_mfma_f32_32x32x16_bf16(a, b, acc[g], 0, 0, 0);
      }
    }
    __builtin_amdgcn_s_setprio(0);
  };

  unsigned short *A0=&Afr[0][0], *A1=&Afr[1][0], *A2=&Afr[2][0];
  unsigned short *B0=&Bfr[0][0], *B1=&Bfr[1][0], *B2=&Bfr[2][0];
  stageA(A0,0);  stageB(B0,0);
  stageA(A1,32); stageB(B1,32);
  for(int s=0; s<15; ++s){
    asm volatile("s_waitcnt vmcnt(3)" ::: "memory");
    __builtin_amdgcn_s_barrier();
    if(s+2<16){ stageA(A2,(s+2)*32); stageB(B2,(s+2)*32); }
    mstep(A0,B0);
    unsigned short* ta=A0; A0=A1; A1=A2; A2=ta;
    unsigned short* tb=B0; B0=B1; B1=B2; B2=tb;
  }
  asm volatile("s_waitcnt vmcnt(0)" ::: "memory");
  __builtin_amdgcn_s_barrier();
  mstep(A0,B0);

  #pragma unroll
  for(int reg=0; reg<16; ++reg){
    int row = r0 + wr*32 + (reg&3) + 8*(reg>>2) + 4*l5;
    int w = row % 25;
    float a0w = asums[w], a1w = asums[25+w], a2w = asums[50+w];
    #pragma unroll
    for(int g=0; g<4; ++g){
      int cc = w2*128 + g*32 + l31;
      float b = br1[cc] + a0w*bg1[cc] + a1w*bg1[256+cc] + a2w*bg1[512+cc];
      featb[(size_t)row*256 + cc] = f2bs(fmaxf(acc[g][reg] + b, 0.f));
    }
  }
}

// ---------------------------------------------------------------------------
// kGC1: graph GEMM1, 128x128 tile, 8 waves, counted-vmcnt pipeline + T5.
// ---------------------------------------------------------------------------
__global__ __launch_bounds__(512,2) void kGC1(
    const unsigned short* __restrict__ xcat, const unsigned short* __restrict__ Wc1,
    const float* __restrict__ bg0, const float* __restrict__ Amat,
    const float* __restrict__ ei, unsigned short* __restrict__ yb)
{
  __shared__ unsigned short Afr[3][8*512];
  __shared__ unsigned short Bfr[3][8*512];
  __shared__ float asums[75];
  const int t = threadIdx.x;
  const int r0 = blockIdx.x*128;
  if(t<75){
    int k=t/25, w=t%25; float s=0.f;
    for(int v=0;v<25;++v) s += ei[k*625+v*25+w]*Amat[k*625+v*25+w];
    asums[t]=s;
  }
  const int lane = t&63, wid = t>>6;
  const int wr = wid>>1, w2 = wid&1;
  const int l31 = lane&31, l5 = lane>>5;
  f32x16 acc[2];
  #pragma unroll
  for(int g=0;g<2;++g)
    #pragma unroll
    for(int j=0;j<16;++j) acc[g][j]=0.f;

  auto stageA = [&](unsigned short* dst, int k0){
    int row = r0 + (wid>>1)*32 + l31;
    int kg = k0 + ((wid&1)*2 + l5)*8;
    stage16(dst + (size_t)(wid*64)*8, lane, xcat + (size_t)row*192 + kg);
  };
  auto stageB = [&](unsigned short* dst, int k0){
    const unsigned short* wt = Wc1 + (size_t)(k0>>5)*4096;
    int off = wid*64;
    stage16(dst + (size_t)off*8, lane, wt + (size_t)(off + lane)*8);
  };
  auto mstep = [&](const unsigned short* Ab, const unsigned short* Bb){
    __builtin_amdgcn_s_setprio(1);
    #pragma unroll
    for(int kh=0; kh<2; ++kh){
      v8bf a = *(const v8bf*)&Ab[(wr*2+kh)*512 + lane*8];
      #pragma unroll
      for(int g=0; g<2; ++g){
        v8bf b = *(const v8bf*)&Bb[((w2*2+g)*2+kh)*512 + lane*8];
        acc[g] = __builtin_amdgcn_mfma_f32_32x32x16_bf16(a, b, acc[g], 0, 0, 0);
      }
    }
    __builtin_amdgcn_s_setprio(0);
  };

  unsigned short *A0=&Afr[0][0], *A1=&Afr[1][0], *A2=&Afr[2][0];
  unsigned short *B0=&Bfr[0][0], *B1=&Bfr[1][0], *B2=&Bfr[2][0];
  stageA(A0,0);  stageB(B0,0);
  stageA(A1,32); stageB(B1,32);
  for(int s=0; s<5; ++s){
    asm volatile("s_waitcnt vmcnt(2)" ::: "memory");
    __builtin_amdgcn_s_barrier();
    if(s+2<6){ stageA(A2,(s+2)*32); stageB(B2,(s+2)*32); }
    mstep(A0,B0);
    unsigned short* ta=A0; A0=A1; A1=A2; A2=ta;
    unsigned short* tb=B0; B0=B1; B1=B2; B2=tb;
  }
  asm volatile("s_waitcnt vmcnt(0)" ::: "memory");
  __builtin_amdgcn_s_barrier();
  mstep(A0,B0);

  #pragma unroll
  for(int reg=0; reg<16; ++reg){
    int row = r0 + wr*32 + (reg&3) + 8*(reg>>2) + 4*l5;
    int w = row % 25;
    float a0w = asums[w], a1w = asums[25+w], a2w = asums[50+w];
    #pragma unroll
    for(int g=0; g<2; ++g){
      int cc = w2*64 + g*32 + l31;
      float b = a0w*bg0[cc] + a1w*bg0[128+cc] + a2w*bg0[256+cc];
      yb[(size_t)row*128 + cc] = f2bs(fmaxf(acc[g][reg] + b, 0.f));
    }
  }
}

// ---------------------------------------------------------------------------
// kFin<MODE>: sum S partials + bias, LSTM pointwise (unchanged)
// ---------------------------------------------------------------------------
template<int MODE>
__global__ __launch_bounds__(256) void kFin(
    const float* __restrict__ part, const float* __restrict__ c0,
    const float* __restrict__ bias, float* __restrict__ out, int S)
{
  constexpr int ROWS = (MODE==1)?Nn:Bn;
  const int row = blockIdx.x, u = threadIdx.x;
  size_t hoff = hoffOf<MODE>(row);
  int boff = (MODE==1)?((row&1)*1024):0;
  float zg4[4] = { bias[boff+u], bias[boff+256+u], bias[boff+512+u], bias[boff+768+u] };
  for(int s=0;s<S;++s){
    const float* p = part + ((size_t)s*ROWS + row)*1024;
    #pragma unroll
    for(int g=0;g<4;++g) zg4[g] += p[g*256+u];
  }
  float iv=hsig(zg4[0]), fv=hsig(zg4[1]), gv=ftanh(zg4[2]), ov=hsig(zg4[3]);
  float cc = c0[hoff+u];
  float c2 = fv*cc + iv*gv;
  out[hoff+u] = ov*ftanh(c2);
}

extern "C" void kernel_launch(void* const* d_in, const int* in_sizes, int n_in,
                              void* d_out, int out_size, void* d_ws, size_t ws_size,
                              hipStream_t stream)
{
  const float* x   = (const float*)d_in[0];
  const float* h0  = (const float*)d_in[1];
  const float* c0  = (const float*)d_in[2];
  const float* A   = (const float*)d_in[3];
  const float* ei  = (const float*)d_in[4];
  const float* wg0 = (const float*)d_in[5];
  const float* bg0 = (const float*)d_in[6];
  const float* wg1 = (const float*)d_in[7];
  const float* bg1 = (const float*)d_in[8];
  const float* wr1 = (const float*)d_in[9];
  const float* br1 = (const float*)d_in[10];
  const float* kern  = (const float*)d_in[11];
  const float* kernB = (const float*)d_in[12];
  const float* kernW = (const float*)d_in[13];
  const float* rk    = (const float*)d_in[14];
  const float* rkB   = (const float*)d_in[15];
  const float* rkW   = (const float*)d_in[16];
  const float* bias  = (const float*)d_in[17];
  const float* biasB = (const float*)d_in[18];
  const float* biasW = (const float*)d_in[19];
  float* out = (float*)d_out;
  char* wsb  = (char*)d_ws;

  // ws layout (bytes), total 149.7 MB (< 157.3 MB proven):
  //  [0, 52428800)                        featb (bf16, 102400x256)
  //  [52428800, 94158848)                 weights: WbJ|WbB|WbW|Wc2|Wc1 (41.73 MB)
  //  [94158848, 146587648)   dyn region:  graph temps (ycat|yb; xcat overlays)
  //                                       then h0bJ (joint) then part (split-K)
  //  [146587648, 149733376)               hB (2 MB) | hW (1 MB)
  unsigned short* featb = (unsigned short*)wsb;
  unsigned short* WbJ = (unsigned short*)(wsb + 52428800);
  unsigned short* WbB = WbJ + 524288;
  unsigned short* WbW = WbB + 6815744;
  unsigned short* Wc2 = WbW + 13369344;
  unsigned short* Wc1 = Wc2 + 131072;
  char* dyn = wsb + 94158848;
  unsigned short* ycat = (unsigned short*)dyn;
  unsigned short* xcat = ycat;
  unsigned short* yb   = (unsigned short*)(dyn + 39321600);
  unsigned short* h0bJ = (unsigned short*)dyn;                  // after graph phase
  float* part = (float*)dyn;                                    // after joint
  unsigned short* hB = (unsigned short*)(wsb + 146587648);
  unsigned short* hW = hB + 1048576;

  // weights -> bf16 fragment order
  kConvW<0><<<(524288+255)/256,   256, 0, stream>>>(kern,  rk,  WbJ, 524288);
  kConvW<1><<<(6815744+255)/256,  256, 0, stream>>>(kernB, rkB, WbB, 6815744);
  kConvW<2><<<(13369344+255)/256, 256, 0, stream>>>(kernW, rkW, WbW, 13369344);
  kConvW<3><<<(131072+255)/256,   256, 0, stream>>>(wg1, wr1, Wc2, 131072);
  kConvW<4><<<(24576+255)/256,    256, 0, stream>>>(wg0, nullptr, Wc1, 24576);
  // h -> bf16 (hB/hW independent region; can run now)
  kConvH<1><<<(262144+255)/256, 256, 0, stream>>>(h0, hB, 262144);
  kConvH<2><<<(131072+255)/256, 256, 0, stream>>>(h0, hW, 131072);

  for(int c=0;c<NCH;++c){
    const float* xc = x + (size_t)c*NnC*(Vv*Dd);
    kMix<64,float>          <<<NnC, 192, 0, stream>>>(xc, A, ei, 0, xcat);
    kGC1<<<RCn/128, 512, 0, stream>>>(xcat, Wc1, bg0, A, ei, yb);
    kMix<128,unsigned short><<<NnC, 384, 0, stream>>>(yb, A, ei, 1875, ycat);
    kGC2<<<RCn/128, 512, 0, stream>>>(ycat, yb, Wc2, bg1, br1, A, ei,
                                      featb + (size_t)c*RCn*256);
  }
  // joint h -> bf16 into dyn (graph temps now dead)
  kConvH<0><<<(6553600+255)/256, 256, 0, stream>>>(h0, h0bJ, 6553600);
  // joint: 128-row 8-wave blocks, WT=0 fused epilogue (3200 blocks)
  kLSTMm<0,0><<<(N3/128)*4, 512, 0, stream>>>(featb, h0bJ, c0, WbJ, bias, out, 512);
  // body: split-K S=3 (KC=2240), WT=1 64x64 waves, (32*4) x 3
  kLSTMm<1,1><<<dim3((Nn/128)*4,3), 512, 0, stream>>>(featb, hB, nullptr, WbB, nullptr, part, 2240);
  kFin<1><<<Nn, 256, 0, stream>>>(part, c0, biasB, out, 3);
  // whole: split-K S=6 (KC=2176), WT=1 64x64 waves, (16*4) x 6
  kLSTMm<2,1><<<dim3((Bn/128)*4,6), 512, 0, stream>>>(featb, hW, nullptr, WbW, nullptr, part, 2176);
  kFin<2><<<Bn, 256, 0, stream>>>(part, c0, biasW, out, 6);
}

// Round 19
// 673.184 us; speedup vs baseline: 1.0236x; 1.0236x over previous
//
#include <hip/hip_runtime.h>
#include <hip/hip_bf16.h>
#include <math.h>

// Problem constants
constexpr int Bn = 2048, Mm = 2, Vv = 25, Dd = 64;
constexpr int C1 = 128, C2 = 256, Kk = 3, Uu = 256;
constexpr int NJ = Mm*Vv*Uu;     // 12800
constexpr int NBd = Mm*Uu;       // 512
constexpr int SD = NJ+NBd+Uu;    // 13568
constexpr int Nn = Bn*Mm;        // 4096
constexpr int N3 = Nn*Vv;        // 102400
constexpr int NCH = 2;
constexpr int NnC = Nn/NCH;      // 2048
constexpr int RCn = NnC*Vv;      // 51200 rows per chunk

typedef __bf16 v8bf __attribute__((ext_vector_type(8)));
typedef float f32x16 __attribute__((ext_vector_type(16)));

__device__ __forceinline__ float hsig(float z){ return fminf(fmaxf(0.2f*z+0.5f,0.f),1.f); }
__device__ __forceinline__ float ftanh(float x){
  float e = __expf(2.f*x);
  return 1.f - 2.f*__frcp_rn(e+1.f);
}
__device__ __forceinline__ unsigned short f2bs(float x){
  __hip_bfloat16 h = __float2bfloat16(x);
  unsigned short s; __builtin_memcpy(&s, &h, 2); return s;
}
__device__ __forceinline__ float bs2f(unsigned short s){
  unsigned u = ((unsigned)s)<<16; float f; __builtin_memcpy(&f,&u,4); return f;
}

// Async global->LDS 16B: dst_base is the wave-uniform frag base; HW writes
// base + lane*16.
#if defined(__has_builtin)
#if __has_builtin(__builtin_amdgcn_global_load_lds)
#define HAS_ALD 1
#endif
#endif
#ifndef HAS_ALD
#define HAS_ALD 0
#endif
__device__ __forceinline__ void stage16(unsigned short* dst_base, int lane, const void* src){
#if HAS_ALD
  __builtin_amdgcn_global_load_lds(
      (const __attribute__((address_space(1))) unsigned int*)src,
      (__attribute__((address_space(3))) unsigned int*)dst_base, 16, 0, 0);
#else
  *(uint4*)(dst_base + lane*8) = *(const uint4*)src;
#endif
}

// ---------------------------------------------------------------------------
// kMix<SW,TI>: v-mixing by adjacency (unchanged, verified)
// ---------------------------------------------------------------------------
template<int SW, typename TI>
__global__ __launch_bounds__(SW*3) void kMix(
    const TI* __restrict__ src, const float* __restrict__ Amat,
    const float* __restrict__ ei, int eoff, unsigned short* __restrict__ dst)
{
  __shared__ float xs[Vv*SW];
  __shared__ float as[Kk*Vv*Vv];
  const int n = blockIdx.x, t = threadIdx.x;
  const TI* srow = src + (size_t)n*(Vv*SW);
  for(int i=t;i<Vv*SW;i+=SW*3){
    if constexpr (sizeof(TI)==2) xs[i]=bs2f((unsigned short)srow[i]);
    else xs[i]=srow[i];
  }
  for(int i=t;i<Kk*Vv*Vv;i+=SW*3) as[i]=ei[eoff+i]*Amat[i];
  __syncthreads();
  const int k = t/SW, d = t%SW;
  float acc[Vv];
  #pragma unroll
  for(int w=0;w<Vv;++w) acc[w]=0.f;
  for(int v=0;v<Vv;++v){
    float xv = xs[v*SW+d];
    const float* ap = &as[k*625 + v*25];
    #pragma unroll
    for(int w=0;w<Vv;++w) acc[w] += ap[w]*xv;
  }
  unsigned short* drow = dst + (size_t)n*(Vv*3*SW);
  for(int w=0;w<Vv;++w) drow[w*(3*SW) + t] = f2bs(acc[w]);
}

// ---------------------------------------------------------------------------
// hoffOf: MODE 0 joint, 1 body, 2 whole
// ---------------------------------------------------------------------------
template<int MODE>
__device__ __forceinline__ size_t hoffOf(int row){
  if constexpr (MODE==0){ int b=row/50, j=row-b*50; return (size_t)b*SD + j*256; }
  else if constexpr (MODE==1){ int b=row>>1, m=row&1; return (size_t)b*SD + NJ + m*256; }
  else return (size_t)row*SD + NJ + NBd;
}

// ---------------------------------------------------------------------------
// convW_val<MODE>: fragment-order weight gather (same logic as old kConvW)
// ---------------------------------------------------------------------------
template<int MODE>
__device__ __forceinline__ float convW_val(int i,
    const float* __restrict__ Wm, const float* __restrict__ Wr)
{
  int e = i&7, ln = (i>>3)&63, l31 = ln&31, l5 = ln>>5;
  if constexpr (MODE<=2){
    constexpr int KF = (MODE==0)?256:(MODE==1)?6400:12800;
    constexpr int NKT = (KF+256)/32;
    int fb = (i>>9)&15, kt = (i>>13)%NKT, ublk = i/(NKT*8192);
    int kh = fb&1, cg = fb>>1;
    int k = kt*32 + l5*8 + kh*16 + e;
    int g = cg&3, uu = (cg>>2)*32 + l31;
    int col = g*256 + ublk*64 + uu;
    return (k<KF) ? Wm[(size_t)k*1024+col] : Wr[(size_t)(k-KF)*1024+col];
  } else if constexpr (MODE==3){
    int fb = (i>>9)&15, kt = i>>13;
    int kh = fb&1, cg = fb>>1;
    int k = kt*32 + l5*8 + kh*16 + e;
    int col = cg*32 + l31;
    return (k<384) ? Wm[(size_t)(k&127)*768 + (k>>7)*256 + col]
                   : Wr[(size_t)(k-384)*256 + col];
  } else {
    int fb = (i>>9)&7, kt = i>>12;
    int kh = fb&1, cg = fb>>1;
    int k = kt*32 + l5*8 + kh*16 + e;
    int col = cg*32 + l31;
    return Wm[(size_t)(k&63)*384 + (k>>6)*128 + col];
  }
}

// ---------------------------------------------------------------------------
// kPrep: ALL weight/h converts in ONE launch (was 7 kernels — launch/tail
// elimination).  Flat index ranges: WbJ | WbB | WbW | Wc2 | Wc1 | hB | hW.
// ---------------------------------------------------------------------------
constexpr int PREP_T0 = 524288;            // WbJ
constexpr int PREP_T1 = 6815744;           // WbB
constexpr int PREP_T2 = 13369344;          // WbW
constexpr int PREP_T3 = 131072;            // Wc2
constexpr int PREP_T4 = 24576;             // Wc1
constexpr int PREP_T5 = 262144;            // hB (uint2 units)
constexpr int PREP_T6 = 131072;            // hW (uint2 units)
constexpr int PREP_TOTAL = PREP_T0+PREP_T1+PREP_T2+PREP_T3+PREP_T4+PREP_T5+PREP_T6; // 21258240

__global__ __launch_bounds__(256) void kPrep(
    const float* __restrict__ kern,  const float* __restrict__ rk,
    const float* __restrict__ kernB, const float* __restrict__ rkB,
    const float* __restrict__ kernW, const float* __restrict__ rkW,
    const float* __restrict__ wg1,   const float* __restrict__ wr1,
    const float* __restrict__ wg0,   const float* __restrict__ h0,
    unsigned short* __restrict__ WbJ, unsigned short* __restrict__ WbB,
    unsigned short* __restrict__ WbW, unsigned short* __restrict__ Wc2,
    unsigned short* __restrict__ Wc1, unsigned short* __restrict__ hB,
    unsigned short* __restrict__ hW)
{
  int i = blockIdx.x*256 + threadIdx.x;
  if(i < PREP_T0){ WbJ[i] = f2bs(convW_val<0>(i, kern, rk)); return; }
  i -= PREP_T0;
  if(i < PREP_T1){ WbB[i] = f2bs(convW_val<1>(i, kernB, rkB)); return; }
  i -= PREP_T1;
  if(i < PREP_T2){ WbW[i] = f2bs(convW_val<2>(i, kernW, rkW)); return; }
  i -= PREP_T2;
  if(i < PREP_T3){ Wc2[i] = f2bs(convW_val<3>(i, wg1, wr1)); return; }
  i -= PREP_T3;
  if(i < PREP_T4){ Wc1[i] = f2bs(convW_val<4>(i, wg0, nullptr)); return; }
  i -= PREP_T4;
  if(i < PREP_T5){
    int row = i>>6, k4 = (i&63)*4;
    const float* s = h0 + hoffOf<1>(row) + k4;
    float4 f = *(const float4*)s;
    uint2 o;
    o.x = (unsigned)f2bs(f.x) | ((unsigned)f2bs(f.y)<<16);
    o.y = (unsigned)f2bs(f.z) | ((unsigned)f2bs(f.w)<<16);
    *(uint2*)(hB + (size_t)i*4) = o; return;
  }
  i -= PREP_T5;
  {
    int row = i>>6, k4 = (i&63)*4;
    const float* s = h0 + hoffOf<2>(row) + k4;
    float4 f = *(const float4*)s;
    uint2 o;
    o.x = (unsigned)f2bs(f.x) | ((unsigned)f2bs(f.y)<<16);
    o.y = (unsigned)f2bs(f.z) | ((unsigned)f2bs(f.w)<<16);
    *(uint2*)(hW + (size_t)i*4) = o;
  }
}

// ---------------------------------------------------------------------------
// kConvH<MODE>: h0 fp32 -> bf16 (still used for MODE 0 after graph phase)
// ---------------------------------------------------------------------------
template<int MODE>
__global__ __launch_bounds__(256) void kConvH(
    const float* __restrict__ h0, unsigned short* __restrict__ dst, int total4)
{
  int i = blockIdx.x*256 + threadIdx.x;
  if(i>=total4) return;
  int row = i>>6, k4 = (i&63)*4;
  const float* s = h0 + hoffOf<MODE>(row) + k4;
  float4 f = *(const float4*)s;
  uint2 o;
  o.x = (unsigned)f2bs(f.x) | ((unsigned)f2bs(f.y)<<16);
  o.y = (unsigned)f2bs(f.z) | ((unsigned)f2bs(f.w)<<16);
  *(uint2*)(dst + (size_t)i*4) = o;
}

// ---------------------------------------------------------------------------
// kLSTMm<MODE,WT>: MFMA bf16 GEMM, block tile 128 rows x 256 staged cols,
// 8 waves (512 thr), counted-vmcnt 3-buffer pipeline (72 KB LDS, 2 blk/CU).
// WT=0: wave tile 32x128 (fused LSTM epilogue).  WT=1: 64x64 (partials).
// ---------------------------------------------------------------------------
template<int MODE, int WT>
__global__ __launch_bounds__(512,2) void kLSTMm(
    const unsigned short* __restrict__ featb, const unsigned short* __restrict__ h0b,
    const float* __restrict__ c0, const unsigned short* __restrict__ Wcat,
    const float* __restrict__ bias, float* __restrict__ outp, int KC)
{
  constexpr int KF = (MODE==0)?256:(MODE==1)?6400:12800;
  constexpr int KT = KF+256;
  constexpr int NKT = KT/32;
  constexpr int ROWS = (MODE==0)?N3:(MODE==1)?Nn:Bn;
  __shared__ unsigned short Afr[3][8*512];
  __shared__ unsigned short Bfr[3][16*512];
  const int t = threadIdx.x;
  const int bx = blockIdx.x;
  const int r0 = (bx>>2)*128;
  const int ublk = bx&3;
  const int z = (MODE==0)?0:blockIdx.y;
  const int kBeg = z*KC, kEnd = min(KT, kBeg+KC);
  const int lane = t&63, wid = t>>6;
  const int l31 = lane&31, l5 = lane>>5;
  const int wr = wid>>1, w2 = wid&1;
  const int wrr = wid>>2, wcc = wid&3;

  constexpr int AC = (WT==0)?4:2;
  constexpr int ARr = (WT==0)?1:2;
  f32x16 acc[ARr][AC];
  #pragma unroll
  for(int i=0;i<ARr;++i)
    #pragma unroll
    for(int j=0;j<AC;++j)
      #pragma unroll
      for(int e=0;e<16;++e) acc[i][j][e]=0.f;

  auto stageA = [&](unsigned short* dstb, int k0){
    int row = r0 + (wid>>1)*32 + l31;
    int kg = k0 + ((wid&1)*2 + l5)*8;
    const unsigned short* src = (kg < KF)
        ? featb + (size_t)row*KF + kg
        : h0b   + (size_t)row*256 + (kg - KF);
    stage16(dstb + (size_t)(wid*64)*8, lane, src);
  };
  auto stageB = [&](unsigned short* dstb, int k0){
    const unsigned short* wt = Wcat + ((size_t)ublk*NKT + (k0>>5))*8192;
    #pragma unroll
    for(int i=0;i<2;++i){
      int off = i*512 + wid*64;
      stage16(dstb + (size_t)off*8, lane, wt + (size_t)(off + lane)*8);
    }
  };
  auto mstep = [&](const unsigned short* Ab, const unsigned short* Bb){
    __builtin_amdgcn_s_setprio(1);
    if constexpr (WT==0){
      #pragma unroll
      for(int kh=0; kh<2; ++kh){
        v8bf a = *(const v8bf*)&Ab[(wr*2+kh)*512 + lane*8];
        #pragma unroll
        for(int g=0; g<4; ++g){
          v8bf b = *(const v8bf*)&Bb[((w2*4+g)*2+kh)*512 + lane*8];
          acc[0][g] = __builtin_amdgcn_mfma_f32_32x32x16_bf16(a, b, acc[0][g], 0, 0, 0);
        }
      }
    } else {
      #pragma unroll
      for(int kh=0; kh<2; ++kh){
        v8bf a[2], b[2];
        #pragma unroll
        for(int rq=0;rq<2;++rq)
          a[rq] = *(const v8bf*)&Ab[((wrr*2+rq)*2+kh)*512 + lane*8];
        #pragma unroll
        for(int cq=0;cq<2;++cq)
          b[cq] = *(const v8bf*)&Bb[((wcc*2+cq)*2+kh)*512 + lane*8];
        #pragma unroll
        for(int rq=0;rq<2;++rq)
          #pragma unroll
          for(int cq=0;cq<2;++cq)
            acc[rq][cq] = __builtin_amdgcn_mfma_f32_32x32x16_bf16(a[rq], b[cq], acc[rq][cq], 0, 0, 0);
      }
    }
    __builtin_amdgcn_s_setprio(0);
  };

  unsigned short *A0=&Afr[0][0], *A1=&Afr[1][0], *A2=&Afr[2][0];
  unsigned short *B0=&Bfr[0][0], *B1=&Bfr[1][0], *B2=&Bfr[2][0];
  const int nst = (kEnd-kBeg)>>5;
  stageA(A0, kBeg);    stageB(B0, kBeg);
  stageA(A1, kBeg+32); stageB(B1, kBeg+32);
  for(int s=0; s<nst-1; ++s){
    asm volatile("s_waitcnt vmcnt(3)" ::: "memory");
    __builtin_amdgcn_s_barrier();
    if(s+2<nst){ stageA(A2, kBeg+(s+2)*32); stageB(B2, kBeg+(s+2)*32); }
    mstep(A0, B0);
    unsigned short* ta=A0; A0=A1; A1=A2; A2=ta;
    unsigned short* tb=B0; B0=B1; B1=B2; B2=tb;
  }
  asm volatile("s_waitcnt vmcnt(0)" ::: "memory");
  __builtin_amdgcn_s_barrier();
  mstep(A0, B0);

  if constexpr (MODE==0){
    const int u = ublk*64 + w2*32 + l31;
    #pragma unroll
    for(int reg=0; reg<16; ++reg){
      int row = r0 + wr*32 + (reg&3) + 8*(reg>>2) + 4*l5;
      int b = row/50, j = row - b*50;
      size_t hoff = (size_t)b*SD + j*256;
      int boff = j*1024;
      float zi = acc[0][0][reg] + bias[boff + u];
      float zf = acc[0][1][reg] + bias[boff + 256 + u];
      float zg = acc[0][2][reg] + bias[boff + 512 + u];
      float zo = acc[0][3][reg] + bias[boff + 768 + u];
      float iv=hsig(zi), fv=hsig(zf), gv=ftanh(zg), ov=hsig(zo);
      float cc = c0[hoff+u];
      float c2 = fv*cc + iv*gv;
      outp[hoff+u] = ov*ftanh(c2);
    }
  } else {
    #pragma unroll
    for(int rq=0;rq<2;++rq){
      #pragma unroll
      for(int cq=0;cq<2;++cq){
        int cg = wcc*2+cq, g = cg&3, uh = cg>>2;
        int u = ublk*64 + uh*32 + l31;
        #pragma unroll
        for(int reg=0; reg<16; ++reg){
          int row = r0 + (wrr*2+rq)*32 + (reg&3) + 8*(reg>>2) + 4*l5;
          outp[((size_t)z*ROWS + row)*1024 + g*256 + u] = acc[rq][cq][reg];
        }
      }
    }
  }
}

// ---------------------------------------------------------------------------
// kGC2: graph GEMM2, 128x256 tile, 8 waves, counted-vmcnt pipeline + T5.
// ---------------------------------------------------------------------------
__global__ __launch_bounds__(512,2) void kGC2(
    const unsigned short* __restrict__ ycat, const unsigned short* __restrict__ yb,
    const unsigned short* __restrict__ Wc2, const float* __restrict__ bg1,
    const float* __restrict__ br1, const float* __restrict__ Amat,
    const float* __restrict__ ei, unsigned short* __restrict__ featb)
{
  __shared__ unsigned short Afr[3][8*512];
  __shared__ unsigned short Bfr[3][16*512];
  __shared__ float asums[75];
  const int t = threadIdx.x;
  const int r0 = blockIdx.x*128;
  if(t<75){
    int k=t/25, w=t%25; float s=0.f;
    for(int v=0;v<25;++v) s += ei[1875 + k*625+v*25+w]*Amat[k*625+v*25+w];
    asums[t]=s;
  }
  const int lane = t&63, wid = t>>6;
  const int wr = wid>>1, w2 = wid&1;
  const int l31 = lane&31, l5 = lane>>5;
  f32x16 acc[4];
  #pragma unroll
  for(int g=0;g<4;++g)
    #pragma unroll
    for(int j=0;j<16;++j) acc[g][j]=0.f;

  auto stageA = [&](unsigned short* dst, int k0){
    int row = r0 + (wid>>1)*32 + l31;
    int kg = k0 + ((wid&1)*2 + l5)*8;
    const unsigned short* src = (kg<384) ? ycat + (size_t)row*384 + kg
                                         : yb   + (size_t)row*128 + (kg-384);
    stage16(dst + (size_t)(wid*64)*8, lane, src);
  };
  auto stageB = [&](unsigned short* dst, int k0){
    const unsigned short* wt = Wc2 + (size_t)(k0>>5)*8192;
    #pragma unroll
    for(int i=0;i<2;++i){
      int off = i*512 + wid*64;
      stage16(dst + (size_t)off*8, lane, wt + (size_t)(off + lane)*8);
    }
  };
  auto mstep = [&](const unsigned short* Ab, const unsigned short* Bb){
    __builtin_amdgcn_s_setprio(1);
    #pragma unroll
    for(int kh=0; kh<2; ++kh){
      v8bf a = *(const v8bf*)&Ab[(wr*2+kh)*512 + lane*8];
      #pragma unroll
      for(int g=0; g<4; ++g){
        v8bf b = *(const v8bf*)&Bb[((w2*4+g)*2+kh)*512 + lane*8];
        acc[g] = __builtin_amdgcn_mfma_f32_32x32x16_bf16(a, b, acc[g], 0, 0, 0);
      }
    }
    __builtin_amdgcn_s_setprio(0);
  };

  unsigned short *A0=&Afr[0][0], *A1=&Afr[1][0], *A2=&Afr[2][0];
  unsigned short *B0=&Bfr[0][0], *B1=&Bfr[1][0], *B2=&Bfr[2][0];
  stageA(A0,0);  stageB(B0,0);
  stageA(A1,32); stageB(B1,32);
  for(int s=0; s<15; ++s){
    asm volatile("s_waitcnt vmcnt(3)" ::: "memory");
    __builtin_amdgcn_s_barrier();
    if(s+2<16){ stageA(A2,(s+2)*32); stageB(B2,(s+2)*32); }
    mstep(A0,B0);
    unsigned short* ta=A0; A0=A1; A1=A2; A2=ta;
    unsigned short* tb=B0; B0=B1; B1=B2; B2=tb;
  }
  asm volatile("s_waitcnt vmcnt(0)" ::: "memory");
  __builtin_amdgcn_s_barrier();
  mstep(A0,B0);

  #pragma unroll
  for(int reg=0; reg<16; ++reg){
    int row = r0 + wr*32 + (reg&3) + 8*(reg>>2) + 4*l5;
    int w = row % 25;
    float a0w = asums[w], a1w = asums[25+w], a2w = asums[50+w];
    #pragma unroll
    for(int g=0; g<4; ++g){
      int cc = w2*128 + g*32 + l31;
      float b = br1[cc] + a0w*bg1[cc] + a1w*bg1[256+cc] + a2w*bg1[512+cc];
      featb[(size_t)row*256 + cc] = f2bs(fmaxf(acc[g][reg] + b, 0.f));
    }
  }
}

// ---------------------------------------------------------------------------
// kGC1: graph GEMM1, 128x128 tile, 8 waves, counted-vmcnt pipeline + T5.
// ---------------------------------------------------------------------------
__global__ __launch_bounds__(512,2) void kGC1(
    const unsigned short* __restrict__ xcat, const unsigned short* __restrict__ Wc1,
    const float* __restrict__ bg0, const float* __restrict__ Amat,
    const float* __restrict__ ei, unsigned short* __restrict__ yb)
{
  __shared__ unsigned short Afr[3][8*512];
  __shared__ unsigned short Bfr[3][8*512];
  __shared__ float asums[75];
  const int t = threadIdx.x;
  const int r0 = blockIdx.x*128;
  if(t<75){
    int k=t/25, w=t%25; float s=0.f;
    for(int v=0;v<25;++v) s += ei[k*625+v*25+w]*Amat[k*625+v*25+w];
    asums[t]=s;
  }
  const int lane = t&63, wid = t>>6;
  const int wr = wid>>1, w2 = wid&1;
  const int l31 = lane&31, l5 = lane>>5;
  f32x16 acc[2];
  #pragma unroll
  for(int g=0;g<2;++g)
    #pragma unroll
    for(int j=0;j<16;++j) acc[g][j]=0.f;

  auto stageA = [&](unsigned short* dst, int k0){
    int row = r0 + (wid>>1)*32 + l31;
    int kg = k0 + ((wid&1)*2 + l5)*8;
    stage16(dst + (size_t)(wid*64)*8, lane, xcat + (size_t)row*192 + kg);
  };
  auto stageB = [&](unsigned short* dst, int k0){
    const unsigned short* wt = Wc1 + (size_t)(k0>>5)*4096;
    int off = wid*64;
    stage16(dst + (size_t)off*8, lane, wt + (size_t)(off + lane)*8);
  };
  auto mstep = [&](const unsigned short* Ab, const unsigned short* Bb){
    __builtin_amdgcn_s_setprio(1);
    #pragma unroll
    for(int kh=0; kh<2; ++kh){
      v8bf a = *(const v8bf*)&Ab[(wr*2+kh)*512 + lane*8];
      #pragma unroll
      for(int g=0; g<2; ++g){
        v8bf b = *(const v8bf*)&Bb[((w2*2+g)*2+kh)*512 + lane*8];
        acc[g] = __builtin_amdgcn_mfma_f32_32x32x16_bf16(a, b, acc[g], 0, 0, 0);
      }
    }
    __builtin_amdgcn_s_setprio(0);
  };

  unsigned short *A0=&Afr[0][0], *A1=&Afr[1][0], *A2=&Afr[2][0];
  unsigned short *B0=&Bfr[0][0], *B1=&Bfr[1][0], *B2=&Bfr[2][0];
  stageA(A0,0);  stageB(B0,0);
  stageA(A1,32); stageB(B1,32);
  for(int s=0; s<5; ++s){
    asm volatile("s_waitcnt vmcnt(2)" ::: "memory");
    __builtin_amdgcn_s_barrier();
    if(s+2<6){ stageA(A2,(s+2)*32); stageB(B2,(s+2)*32); }
    mstep(A0,B0);
    unsigned short* ta=A0; A0=A1; A1=A2; A2=ta;
    unsigned short* tb=B0; B0=B1; B1=B2; B2=tb;
  }
  asm volatile("s_waitcnt vmcnt(0)" ::: "memory");
  __builtin_amdgcn_s_barrier();
  mstep(A0,B0);

  #pragma unroll
  for(int reg=0; reg<16; ++reg){
    int row = r0 + wr*32 + (reg&3) + 8*(reg>>2) + 4*l5;
    int w = row % 25;
    float a0w = asums[w], a1w = asums[25+w], a2w = asums[50+w];
    #pragma unroll
    for(int g=0; g<2; ++g){
      int cc = w2*64 + g*32 + l31;
      float b = a0w*bg0[cc] + a1w*bg0[128+cc] + a2w*bg0[256+cc];
      yb[(size_t)row*128 + cc] = f2bs(fmaxf(acc[g][reg] + b, 0.f));
    }
  }
}

// ---------------------------------------------------------------------------
// kFin<MODE>: sum S partials + bias, LSTM pointwise (unchanged)
// ---------------------------------------------------------------------------
template<int MODE>
__global__ __launch_bounds__(256) void kFin(
    const float* __restrict__ part, const float* __restrict__ c0,
    const float* __restrict__ bias, float* __restrict__ out, int S)
{
  constexpr int ROWS = (MODE==1)?Nn:Bn;
  const int row = blockIdx.x, u = threadIdx.x;
  size_t hoff = hoffOf<MODE>(row);
  int boff = (MODE==1)?((row&1)*1024):0;
  float zg4[4] = { bias[boff+u], bias[boff+256+u], bias[boff+512+u], bias[boff+768+u] };
  for(int s=0;s<S;++s){
    const float* p = part + ((size_t)s*ROWS + row)*1024;
    #pragma unroll
    for(int g=0;g<4;++g) zg4[g] += p[g*256+u];
  }
  float iv=hsig(zg4[0]), fv=hsig(zg4[1]), gv=ftanh(zg4[2]), ov=hsig(zg4[3]);
  float cc = c0[hoff+u];
  float c2 = fv*cc + iv*gv;
  out[hoff+u] = ov*ftanh(c2);
}

extern "C" void kernel_launch(void* const* d_in, const int* in_sizes, int n_in,
                              void* d_out, int out_size, void* d_ws, size_t ws_size,
                              hipStream_t stream)
{
  const float* x   = (const float*)d_in[0];
  const float* h0  = (const float*)d_in[1];
  const float* c0  = (const float*)d_in[2];
  const float* A   = (const float*)d_in[3];
  const float* ei  = (const float*)d_in[4];
  const float* wg0 = (const float*)d_in[5];
  const float* bg0 = (const float*)d_in[6];
  const float* wg1 = (const float*)d_in[7];
  const float* bg1 = (const float*)d_in[8];
  const float* wr1 = (const float*)d_in[9];
  const float* br1 = (const float*)d_in[10];
  const float* kern  = (const float*)d_in[11];
  const float* kernB = (const float*)d_in[12];
  const float* kernW = (const float*)d_in[13];
  const float* rk    = (const float*)d_in[14];
  const float* rkB   = (const float*)d_in[15];
  const float* rkW   = (const float*)d_in[16];
  const float* bias  = (const float*)d_in[17];
  const float* biasB = (const float*)d_in[18];
  const float* biasW = (const float*)d_in[19];
  float* out = (float*)d_out;
  char* wsb  = (char*)d_ws;

  // ws layout (bytes), total 149.7 MB (< 157.3 MB proven):
  //  [0, 52428800)                        featb (bf16, 102400x256)
  //  [52428800, 94158848)                 weights: WbJ|WbB|WbW|Wc2|Wc1 (41.73 MB)
  //  [94158848, 146587648)   dyn region:  graph temps (ycat|yb; xcat overlays)
  //                                       then h0bJ (joint) then part (split-K)
  //  [146587648, 149733376)               hB (2 MB) | hW (1 MB)
  unsigned short* featb = (unsigned short*)wsb;
  unsigned short* WbJ = (unsigned short*)(wsb + 52428800);
  unsigned short* WbB = WbJ + 524288;
  unsigned short* WbW = WbB + 6815744;
  unsigned short* Wc2 = WbW + 13369344;
  unsigned short* Wc1 = Wc2 + 131072;
  char* dyn = wsb + 94158848;
  unsigned short* ycat = (unsigned short*)dyn;
  unsigned short* xcat = ycat;
  unsigned short* yb   = (unsigned short*)(dyn + 39321600);
  unsigned short* h0bJ = (unsigned short*)dyn;                  // after graph phase
  float* part = (float*)dyn;                                    // after joint
  unsigned short* hB = (unsigned short*)(wsb + 146587648);
  unsigned short* hW = hB + 1048576;

  // ALL weight/h converts in one launch (was 7)
  kPrep<<<PREP_TOTAL/256, 256, 0, stream>>>(
      kern, rk, kernB, rkB, kernW, rkW, wg1, wr1, wg0, h0,
      WbJ, WbB, WbW, Wc2, Wc1, hB, hW);

  for(int c=0;c<NCH;++c){
    const float* xc = x + (size_t)c*NnC*(Vv*Dd);
    kMix<64,float>          <<<NnC, 192, 0, stream>>>(xc, A, ei, 0, xcat);
    kGC1<<<RCn/128, 512, 0, stream>>>(xcat, Wc1, bg0, A, ei, yb);
    kMix<128,unsigned short><<<NnC, 384, 0, stream>>>(yb, A, ei, 1875, ycat);
    kGC2<<<RCn/128, 512, 0, stream>>>(ycat, yb, Wc2, bg1, br1, A, ei,
                                      featb + (size_t)c*RCn*256);
  }
  // joint h -> bf16 into dyn (graph temps now dead)
  kConvH<0><<<(6553600+255)/256, 256, 0, stream>>>(h0, h0bJ, 6553600);
  // joint: 128-row 8-wave blocks, WT=0 fused epilogue (3200 blocks)
  kLSTMm<0,0><<<(N3/128)*4, 512, 0, stream>>>(featb, h0bJ, c0, WbJ, bias, out, 512);
  // body: split-K S=3 (KC=2240), WT=1 64x64 waves, (32*4) x 3
  kLSTMm<1,1><<<dim3((Nn/128)*4,3), 512, 0, stream>>>(featb, hB, nullptr, WbB, nullptr, part, 2240);
  kFin<1><<<Nn, 256, 0, stream>>>(part, c0, biasB, out, 3);
  // whole: split-K S=6 (KC=2176), WT=1 64x64 waves, (16*4) x 6
  kLSTMm<2,1><<<dim3((Bn/128)*4,6), 512, 0, stream>>>(featb, hW, nullptr, WbW, nullptr, part, 2176);
  kFin<2><<<Bn, 256, 0, stream>>>(part, c0, biasW, out, 6);
}

// Round 20
// 672.418 us; speedup vs baseline: 1.0247x; 1.0011x over previous
//
#include <hip/hip_runtime.h>
#include <hip/hip_bf16.h>
#include <math.h>

// Problem constants
constexpr int Bn = 2048, Mm = 2, Vv = 25, Dd = 64;
constexpr int C1 = 128, C2 = 256, Kk = 3, Uu = 256;
constexpr int NJ = Mm*Vv*Uu;     // 12800
constexpr int NBd = Mm*Uu;       // 512
constexpr int SD = NJ+NBd+Uu;    // 13568
constexpr int Nn = Bn*Mm;        // 4096
constexpr int N3 = Nn*Vv;        // 102400
constexpr int NCH = 2;
constexpr int NnC = Nn/NCH;      // 2048
constexpr int RCn = NnC*Vv;      // 51200 rows per chunk

typedef __bf16 v8bf __attribute__((ext_vector_type(8)));
typedef float f32x16 __attribute__((ext_vector_type(16)));

__device__ __forceinline__ float hsig(float z){ return fminf(fmaxf(0.2f*z+0.5f,0.f),1.f); }
__device__ __forceinline__ float ftanh(float x){
  float e = __expf(2.f*x);
  return 1.f - 2.f*__frcp_rn(e+1.f);
}
__device__ __forceinline__ unsigned short f2bs(float x){
  __hip_bfloat16 h = __float2bfloat16(x);
  unsigned short s; __builtin_memcpy(&s, &h, 2); return s;
}
__device__ __forceinline__ float bs2f(unsigned short s){
  unsigned u = ((unsigned)s)<<16; float f; __builtin_memcpy(&f,&u,4); return f;
}

// Async global->LDS 16B: dst_base is the wave-uniform frag base; HW writes
// base + lane*16.
#if defined(__has_builtin)
#if __has_builtin(__builtin_amdgcn_global_load_lds)
#define HAS_ALD 1
#endif
#endif
#ifndef HAS_ALD
#define HAS_ALD 0
#endif
__device__ __forceinline__ void stage16(unsigned short* dst_base, int lane, const void* src){
#if HAS_ALD
  __builtin_amdgcn_global_load_lds(
      (const __attribute__((address_space(1))) unsigned int*)src,
      (__attribute__((address_space(3))) unsigned int*)dst_base, 16, 0, 0);
#else
  *(uint4*)(dst_base + lane*8) = *(const uint4*)src;
#endif
}

// ---------------------------------------------------------------------------
// kMix<SW,TI>: v-mixing by adjacency (unchanged, verified)
// ---------------------------------------------------------------------------
template<int SW, typename TI>
__global__ __launch_bounds__(SW*3) void kMix(
    const TI* __restrict__ src, const float* __restrict__ Amat,
    const float* __restrict__ ei, int eoff, unsigned short* __restrict__ dst)
{
  __shared__ float xs[Vv*SW];
  __shared__ float as[Kk*Vv*Vv];
  const int n = blockIdx.x, t = threadIdx.x;
  const TI* srow = src + (size_t)n*(Vv*SW);
  for(int i=t;i<Vv*SW;i+=SW*3){
    if constexpr (sizeof(TI)==2) xs[i]=bs2f((unsigned short)srow[i]);
    else xs[i]=srow[i];
  }
  for(int i=t;i<Kk*Vv*Vv;i+=SW*3) as[i]=ei[eoff+i]*Amat[i];
  __syncthreads();
  const int k = t/SW, d = t%SW;
  float acc[Vv];
  #pragma unroll
  for(int w=0;w<Vv;++w) acc[w]=0.f;
  for(int v=0;v<Vv;++v){
    float xv = xs[v*SW+d];
    const float* ap = &as[k*625 + v*25];
    #pragma unroll
    for(int w=0;w<Vv;++w) acc[w] += ap[w]*xv;
  }
  unsigned short* drow = dst + (size_t)n*(Vv*3*SW);
  for(int w=0;w<Vv;++w) drow[w*(3*SW) + t] = f2bs(acc[w]);
}

// ---------------------------------------------------------------------------
// hoffOf: MODE 0 joint, 1 body, 2 whole
// ---------------------------------------------------------------------------
template<int MODE>
__device__ __forceinline__ size_t hoffOf(int row){
  if constexpr (MODE==0){ int b=row/50, j=row-b*50; return (size_t)b*SD + j*256; }
  else if constexpr (MODE==1){ int b=row>>1, m=row&1; return (size_t)b*SD + NJ + m*256; }
  else return (size_t)row*SD + NJ + NBd;
}

// ---------------------------------------------------------------------------
// convW_val<MODE>: fragment-order weight gather
// ---------------------------------------------------------------------------
template<int MODE>
__device__ __forceinline__ float convW_val(int i,
    const float* __restrict__ Wm, const float* __restrict__ Wr)
{
  int e = i&7, ln = (i>>3)&63, l31 = ln&31, l5 = ln>>5;
  if constexpr (MODE<=2){
    constexpr int KF = (MODE==0)?256:(MODE==1)?6400:12800;
    constexpr int NKT = (KF+256)/32;
    int fb = (i>>9)&15, kt = (i>>13)%NKT, ublk = i/(NKT*8192);
    int kh = fb&1, cg = fb>>1;
    int k = kt*32 + l5*8 + kh*16 + e;
    int g = cg&3, uu = (cg>>2)*32 + l31;
    int col = g*256 + ublk*64 + uu;
    return (k<KF) ? Wm[(size_t)k*1024+col] : Wr[(size_t)(k-KF)*1024+col];
  } else if constexpr (MODE==3){
    int fb = (i>>9)&15, kt = i>>13;
    int kh = fb&1, cg = fb>>1;
    int k = kt*32 + l5*8 + kh*16 + e;
    int col = cg*32 + l31;
    return (k<384) ? Wm[(size_t)(k&127)*768 + (k>>7)*256 + col]
                   : Wr[(size_t)(k-384)*256 + col];
  } else {
    int fb = (i>>9)&7, kt = i>>12;
    int kh = fb&1, cg = fb>>1;
    int k = kt*32 + l5*8 + kh*16 + e;
    int col = cg*32 + l31;
    return Wm[(size_t)(k&63)*384 + (k>>6)*128 + col];
  }
}

// ---------------------------------------------------------------------------
// kPrep: ALL weight/h converts in ONE launch.
// ---------------------------------------------------------------------------
constexpr int PREP_T0 = 524288;            // WbJ
constexpr int PREP_T1 = 6815744;           // WbB
constexpr int PREP_T2 = 13369344;          // WbW
constexpr int PREP_T3 = 131072;            // Wc2
constexpr int PREP_T4 = 24576;             // Wc1
constexpr int PREP_T5 = 262144;            // hB (uint2 units)
constexpr int PREP_T6 = 131072;            // hW (uint2 units)
constexpr int PREP_TOTAL = PREP_T0+PREP_T1+PREP_T2+PREP_T3+PREP_T4+PREP_T5+PREP_T6;

__global__ __launch_bounds__(256) void kPrep(
    const float* __restrict__ kern,  const float* __restrict__ rk,
    const float* __restrict__ kernB, const float* __restrict__ rkB,
    const float* __restrict__ kernW, const float* __restrict__ rkW,
    const float* __restrict__ wg1,   const float* __restrict__ wr1,
    const float* __restrict__ wg0,   const float* __restrict__ h0,
    unsigned short* __restrict__ WbJ, unsigned short* __restrict__ WbB,
    unsigned short* __restrict__ WbW, unsigned short* __restrict__ Wc2,
    unsigned short* __restrict__ Wc1, unsigned short* __restrict__ hB,
    unsigned short* __restrict__ hW)
{
  int i = blockIdx.x*256 + threadIdx.x;
  if(i < PREP_T0){ WbJ[i] = f2bs(convW_val<0>(i, kern, rk)); return; }
  i -= PREP_T0;
  if(i < PREP_T1){ WbB[i] = f2bs(convW_val<1>(i, kernB, rkB)); return; }
  i -= PREP_T1;
  if(i < PREP_T2){ WbW[i] = f2bs(convW_val<2>(i, kernW, rkW)); return; }
  i -= PREP_T2;
  if(i < PREP_T3){ Wc2[i] = f2bs(convW_val<3>(i, wg1, wr1)); return; }
  i -= PREP_T3;
  if(i < PREP_T4){ Wc1[i] = f2bs(convW_val<4>(i, wg0, nullptr)); return; }
  i -= PREP_T4;
  if(i < PREP_T5){
    int row = i>>6, k4 = (i&63)*4;
    const float* s = h0 + hoffOf<1>(row) + k4;
    float4 f = *(const float4*)s;
    uint2 o;
    o.x = (unsigned)f2bs(f.x) | ((unsigned)f2bs(f.y)<<16);
    o.y = (unsigned)f2bs(f.z) | ((unsigned)f2bs(f.w)<<16);
    *(uint2*)(hB + (size_t)i*4) = o; return;
  }
  i -= PREP_T5;
  {
    int row = i>>6, k4 = (i&63)*4;
    const float* s = h0 + hoffOf<2>(row) + k4;
    float4 f = *(const float4*)s;
    uint2 o;
    o.x = (unsigned)f2bs(f.x) | ((unsigned)f2bs(f.y)<<16);
    o.y = (unsigned)f2bs(f.z) | ((unsigned)f2bs(f.w)<<16);
    *(uint2*)(hW + (size_t)i*4) = o;
  }
}

// ---------------------------------------------------------------------------
// kConvH<MODE>: h0 fp32 -> bf16 (MODE 0, after graph phase)
// ---------------------------------------------------------------------------
template<int MODE>
__global__ __launch_bounds__(256) void kConvH(
    const float* __restrict__ h0, unsigned short* __restrict__ dst, int total4)
{
  int i = blockIdx.x*256 + threadIdx.x;
  if(i>=total4) return;
  int row = i>>6, k4 = (i&63)*4;
  const float* s = h0 + hoffOf<MODE>(row) + k4;
  float4 f = *(const float4*)s;
  uint2 o;
  o.x = (unsigned)f2bs(f.x) | ((unsigned)f2bs(f.y)<<16);
  o.y = (unsigned)f2bs(f.z) | ((unsigned)f2bs(f.w)<<16);
  *(uint2*)(dst + (size_t)i*4) = o;
}

// ---------------------------------------------------------------------------
// kLSTMm<MODE,WT>: MFMA bf16 GEMM, block tile 128 rows x 256 staged cols,
// 8 waves (512 thr), counted-vmcnt 3-buffer pipeline (72 KB LDS, 2 blk/CU).
// WT=0: wave tile 32x128 (fused LSTM epilogue).  WT=1: 64x64 (partials).
// T1: bijective XCD swizzle on blockIdx.x (gridDim.x % 8 == 0 in all modes)
// so the 4 ublk-siblings of a rowblock land on ONE XCD -> share the A-panel
// in that XCD's L2 (A-reads become L2 hits instead of 4x independent HBM).
// ---------------------------------------------------------------------------
template<int MODE, int WT>
__global__ __launch_bounds__(512,2) void kLSTMm(
    const unsigned short* __restrict__ featb, const unsigned short* __restrict__ h0b,
    const float* __restrict__ c0, const unsigned short* __restrict__ Wcat,
    const float* __restrict__ bias, float* __restrict__ outp, int KC)
{
  constexpr int KF = (MODE==0)?256:(MODE==1)?6400:12800;
  constexpr int KT = KF+256;
  constexpr int NKT = KT/32;
  constexpr int ROWS = (MODE==0)?N3:(MODE==1)?Nn:Bn;
  __shared__ unsigned short Afr[3][8*512];
  __shared__ unsigned short Bfr[3][16*512];
  const int t = threadIdx.x;
  // T1 XCD swizzle: consecutive logical blocks -> same XCD
  const int nbx = gridDim.x;
  const int bxh = blockIdx.x;
  const int bx  = (bxh & 7)*(nbx >> 3) + (bxh >> 3);
  const int r0 = (bx>>2)*128;
  const int ublk = bx&3;
  const int z = (MODE==0)?0:blockIdx.y;
  const int kBeg = z*KC, kEnd = min(KT, kBeg+KC);
  const int lane = t&63, wid = t>>6;
  const int l31 = lane&31, l5 = lane>>5;
  const int wr = wid>>1, w2 = wid&1;
  const int wrr = wid>>2, wcc = wid&3;

  constexpr int AC = (WT==0)?4:2;
  constexpr int ARr = (WT==0)?1:2;
  f32x16 acc[ARr][AC];
  #pragma unroll
  for(int i=0;i<ARr;++i)
    #pragma unroll
    for(int j=0;j<AC;++j)
      #pragma unroll
      for(int e=0;e<16;++e) acc[i][j][e]=0.f;

  auto stageA = [&](unsigned short* dstb, int k0){
    int row = r0 + (wid>>1)*32 + l31;
    int kg = k0 + ((wid&1)*2 + l5)*8;
    const unsigned short* src = (kg < KF)
        ? featb + (size_t)row*KF + kg
        : h0b   + (size_t)row*256 + (kg - KF);
    stage16(dstb + (size_t)(wid*64)*8, lane, src);
  };
  auto stageB = [&](unsigned short* dstb, int k0){
    const unsigned short* wt = Wcat + ((size_t)ublk*NKT + (k0>>5))*8192;
    #pragma unroll
    for(int i=0;i<2;++i){
      int off = i*512 + wid*64;
      stage16(dstb + (size_t)off*8, lane, wt + (size_t)(off + lane)*8);
    }
  };
  auto mstep = [&](const unsigned short* Ab, const unsigned short* Bb){
    __builtin_amdgcn_s_setprio(1);
    if constexpr (WT==0){
      #pragma unroll
      for(int kh=0; kh<2; ++kh){
        v8bf a = *(const v8bf*)&Ab[(wr*2+kh)*512 + lane*8];
        #pragma unroll
        for(int g=0; g<4; ++g){
          v8bf b = *(const v8bf*)&Bb[((w2*4+g)*2+kh)*512 + lane*8];
          acc[0][g] = __builtin_amdgcn_mfma_f32_32x32x16_bf16(a, b, acc[0][g], 0, 0, 0);
        }
      }
    } else {
      #pragma unroll
      for(int kh=0; kh<2; ++kh){
        v8bf a[2], b[2];
        #pragma unroll
        for(int rq=0;rq<2;++rq)
          a[rq] = *(const v8bf*)&Ab[((wrr*2+rq)*2+kh)*512 + lane*8];
        #pragma unroll
        for(int cq=0;cq<2;++cq)
          b[cq] = *(const v8bf*)&Bb[((wcc*2+cq)*2+kh)*512 + lane*8];
        #pragma unroll
        for(int rq=0;rq<2;++rq)
          #pragma unroll
          for(int cq=0;cq<2;++cq)
            acc[rq][cq] = __builtin_amdgcn_mfma_f32_32x32x16_bf16(a[rq], b[cq], acc[rq][cq], 0, 0, 0);
      }
    }
    __builtin_amdgcn_s_setprio(0);
  };

  unsigned short *A0=&Afr[0][0], *A1=&Afr[1][0], *A2=&Afr[2][0];
  unsigned short *B0=&Bfr[0][0], *B1=&Bfr[1][0], *B2=&Bfr[2][0];
  const int nst = (kEnd-kBeg)>>5;
  stageA(A0, kBeg);    stageB(B0, kBeg);
  stageA(A1, kBeg+32); stageB(B1, kBeg+32);
  for(int s=0; s<nst-1; ++s){
    asm volatile("s_waitcnt vmcnt(3)" ::: "memory");
    __builtin_amdgcn_s_barrier();
    if(s+2<nst){ stageA(A2, kBeg+(s+2)*32); stageB(B2, kBeg+(s+2)*32); }
    mstep(A0, B0);
    unsigned short* ta=A0; A0=A1; A1=A2; A2=ta;
    unsigned short* tb=B0; B0=B1; B1=B2; B2=tb;
  }
  asm volatile("s_waitcnt vmcnt(0)" ::: "memory");
  __builtin_amdgcn_s_barrier();
  mstep(A0, B0);

  if constexpr (MODE==0){
    const int u = ublk*64 + w2*32 + l31;
    #pragma unroll
    for(int reg=0; reg<16; ++reg){
      int row = r0 + wr*32 + (reg&3) + 8*(reg>>2) + 4*l5;
      int b = row/50, j = row - b*50;
      size_t hoff = (size_t)b*SD + j*256;
      int boff = j*1024;
      float zi = acc[0][0][reg] + bias[boff + u];
      float zf = acc[0][1][reg] + bias[boff + 256 + u];
      float zg = acc[0][2][reg] + bias[boff + 512 + u];
      float zo = acc[0][3][reg] + bias[boff + 768 + u];
      float iv=hsig(zi), fv=hsig(zf), gv=ftanh(zg), ov=hsig(zo);
      float cc = c0[hoff+u];
      float c2 = fv*cc + iv*gv;
      outp[hoff+u] = ov*ftanh(c2);
    }
  } else {
    #pragma unroll
    for(int rq=0;rq<2;++rq){
      #pragma unroll
      for(int cq=0;cq<2;++cq){
        int cg = wcc*2+cq, g = cg&3, uh = cg>>2;
        int u = ublk*64 + uh*32 + l31;
        #pragma unroll
        for(int reg=0; reg<16; ++reg){
          int row = r0 + (wrr*2+rq)*32 + (reg&3) + 8*(reg>>2) + 4*l5;
          outp[((size_t)z*ROWS + row)*1024 + g*256 + u] = acc[rq][cq][reg];
        }
      }
    }
  }
}

// ---------------------------------------------------------------------------
// kGC2: graph GEMM2, 128x256 tile, 8 waves, counted-vmcnt pipeline + T5.
// ---------------------------------------------------------------------------
__global__ __launch_bounds__(512,2) void kGC2(
    const unsigned short* __restrict__ ycat, const unsigned short* __restrict__ yb,
    const unsigned short* __restrict__ Wc2, const float* __restrict__ bg1,
    const float* __restrict__ br1, const float* __restrict__ Amat,
    const float* __restrict__ ei, unsigned short* __restrict__ featb)
{
  __shared__ unsigned short Afr[3][8*512];
  __shared__ unsigned short Bfr[3][16*512];
  __shared__ float asums[75];
  const int t = threadIdx.x;
  const int r0 = blockIdx.x*128;
  if(t<75){
    int k=t/25, w=t%25; float s=0.f;
    for(int v=0;v<25;++v) s += ei[1875 + k*625+v*25+w]*Amat[k*625+v*25+w];
    asums[t]=s;
  }
  const int lane = t&63, wid = t>>6;
  const int wr = wid>>1, w2 = wid&1;
  const int l31 = lane&31, l5 = lane>>5;
  f32x16 acc[4];
  #pragma unroll
  for(int g=0;g<4;++g)
    #pragma unroll
    for(int j=0;j<16;++j) acc[g][j]=0.f;

  auto stageA = [&](unsigned short* dst, int k0){
    int row = r0 + (wid>>1)*32 + l31;
    int kg = k0 + ((wid&1)*2 + l5)*8;
    const unsigned short* src = (kg<384) ? ycat + (size_t)row*384 + kg
                                         : yb   + (size_t)row*128 + (kg-384);
    stage16(dst + (size_t)(wid*64)*8, lane, src);
  };
  auto stageB = [&](unsigned short* dst, int k0){
    const unsigned short* wt = Wc2 + (size_t)(k0>>5)*8192;
    #pragma unroll
    for(int i=0;i<2;++i){
      int off = i*512 + wid*64;
      stage16(dst + (size_t)off*8, lane, wt + (size_t)(off + lane)*8);
    }
  };
  auto mstep = [&](const unsigned short* Ab, const unsigned short* Bb){
    __builtin_amdgcn_s_setprio(1);
    #pragma unroll
    for(int kh=0; kh<2; ++kh){
      v8bf a = *(const v8bf*)&Ab[(wr*2+kh)*512 + lane*8];
      #pragma unroll
      for(int g=0; g<4; ++g){
        v8bf b = *(const v8bf*)&Bb[((w2*4+g)*2+kh)*512 + lane*8];
        acc[g] = __builtin_amdgcn_mfma_f32_32x32x16_bf16(a, b, acc[g], 0, 0, 0);
      }
    }
    __builtin_amdgcn_s_setprio(0);
  };

  unsigned short *A0=&Afr[0][0], *A1=&Afr[1][0], *A2=&Afr[2][0];
  unsigned short *B0=&Bfr[0][0], *B1=&Bfr[1][0], *B2=&Bfr[2][0];
  stageA(A0,0);  stageB(B0,0);
  stageA(A1,32); stageB(B1,32);
  for(int s=0; s<15; ++s){
    asm volatile("s_waitcnt vmcnt(3)" ::: "memory");
    __builtin_amdgcn_s_barrier();
    if(s+2<16){ stageA(A2,(s+2)*32); stageB(B2,(s+2)*32); }
    mstep(A0,B0);
    unsigned short* ta=A0; A0=A1; A1=A2; A2=ta;
    unsigned short* tb=B0; B0=B1; B1=B2; B2=tb;
  }
  asm volatile("s_waitcnt vmcnt(0)" ::: "memory");
  __builtin_amdgcn_s_barrier();
  mstep(A0,B0);

  #pragma unroll
  for(int reg=0; reg<16; ++reg){
    int row = r0 + wr*32 + (reg&3) + 8*(reg>>2) + 4*l5;
    int w = row % 25;
    float a0w = asums[w], a1w = asums[25+w], a2w = asums[50+w];
    #pragma unroll
    for(int g=0; g<4; ++g){
      int cc = w2*128 + g*32 + l31;
      float b = br1[cc] + a0w*bg1[cc] + a1w*bg1[256+cc] + a2w*bg1[512+cc];
      featb[(size_t)row*256 + cc] = f2bs(fmaxf(acc[g][reg] + b, 0.f));
    }
  }
}

// ---------------------------------------------------------------------------
// kGC1: graph GEMM1, 128x128 tile, 8 waves, counted-vmcnt pipeline + T5.
// ---------------------------------------------------------------------------
__global__ __launch_bounds__(512,2) void kGC1(
    const unsigned short* __restrict__ xcat, const unsigned short* __restrict__ Wc1,
    const float* __restrict__ bg0, const float* __restrict__ Amat,
    const float* __restrict__ ei, unsigned short* __restrict__ yb)
{
  __shared__ unsigned short Afr[3][8*512];
  __shared__ unsigned short Bfr[3][8*512];
  __shared__ float asums[75];
  const int t = threadIdx.x;
  const int r0 = blockIdx.x*128;
  if(t<75){
    int k=t/25, w=t%25; float s=0.f;
    for(int v=0;v<25;++v) s += ei[k*625+v*25+w]*Amat[k*625+v*25+w];
    asums[t]=s;
  }
  const int lane = t&63, wid = t>>6;
  const int wr = wid>>1, w2 = wid&1;
  const int l31 = lane&31, l5 = lane>>5;
  f32x16 acc[2];
  #pragma unroll
  for(int g=0;g<2;++g)
    #pragma unroll
    for(int j=0;j<16;++j) acc[g][j]=0.f;

  auto stageA = [&](unsigned short* dst, int k0){
    int row = r0 + (wid>>1)*32 + l31;
    int kg = k0 + ((wid&1)*2 + l5)*8;
    stage16(dst + (size_t)(wid*64)*8, lane, xcat + (size_t)row*192 + kg);
  };
  auto stageB = [&](unsigned short* dst, int k0){
    const unsigned short* wt = Wc1 + (size_t)(k0>>5)*4096;
    int off = wid*64;
    stage16(dst + (size_t)off*8, lane, wt + (size_t)(off + lane)*8);
  };
  auto mstep = [&](const unsigned short* Ab, const unsigned short* Bb){
    __builtin_amdgcn_s_setprio(1);
    #pragma unroll
    for(int kh=0; kh<2; ++kh){
      v8bf a = *(const v8bf*)&Ab[(wr*2+kh)*512 + lane*8];
      #pragma unroll
      for(int g=0; g<2; ++g){
        v8bf b = *(const v8bf*)&Bb[((w2*2+g)*2+kh)*512 + lane*8];
        acc[g] = __builtin_amdgcn_mfma_f32_32x32x16_bf16(a, b, acc[g], 0, 0, 0);
      }
    }
    __builtin_amdgcn_s_setprio(0);
  };

  unsigned short *A0=&Afr[0][0], *A1=&Afr[1][0], *A2=&Afr[2][0];
  unsigned short *B0=&Bfr[0][0], *B1=&Bfr[1][0], *B2=&Bfr[2][0];
  stageA(A0,0);  stageB(B0,0);
  stageA(A1,32); stageB(B1,32);
  for(int s=0; s<5; ++s){
    asm volatile("s_waitcnt vmcnt(2)" ::: "memory");
    __builtin_amdgcn_s_barrier();
    if(s+2<6){ stageA(A2,(s+2)*32); stageB(B2,(s+2)*32); }
    mstep(A0,B0);
    unsigned short* ta=A0; A0=A1; A1=A2; A2=ta;
    unsigned short* tb=B0; B0=B1; B1=B2; B2=tb;
  }
  asm volatile("s_waitcnt vmcnt(0)" ::: "memory");
  __builtin_amdgcn_s_barrier();
  mstep(A0,B0);

  #pragma unroll
  for(int reg=0; reg<16; ++reg){
    int row = r0 + wr*32 + (reg&3) + 8*(reg>>2) + 4*l5;
    int w = row % 25;
    float a0w = asums[w], a1w = asums[25+w], a2w = asums[50+w];
    #pragma unroll
    for(int g=0; g<2; ++g){
      int cc = w2*64 + g*32 + l31;
      float b = a0w*bg0[cc] + a1w*bg0[128+cc] + a2w*bg0[256+cc];
      yb[(size_t)row*128 + cc] = f2bs(fmaxf(acc[g][reg] + b, 0.f));
    }
  }
}

// ---------------------------------------------------------------------------
// kFin<MODE>: sum S partials + bias, LSTM pointwise (unchanged)
// ---------------------------------------------------------------------------
template<int MODE>
__global__ __launch_bounds__(256) void kFin(
    const float* __restrict__ part, const float* __restrict__ c0,
    const float* __restrict__ bias, float* __restrict__ out, int S)
{
  constexpr int ROWS = (MODE==1)?Nn:Bn;
  const int row = blockIdx.x, u = threadIdx.x;
  size_t hoff = hoffOf<MODE>(row);
  int boff = (MODE==1)?((row&1)*1024):0;
  float zg4[4] = { bias[boff+u], bias[boff+256+u], bias[boff+512+u], bias[boff+768+u] };
  for(int s=0;s<S;++s){
    const float* p = part + ((size_t)s*ROWS + row)*1024;
    #pragma unroll
    for(int g=0;g<4;++g) zg4[g] += p[g*256+u];
  }
  float iv=hsig(zg4[0]), fv=hsig(zg4[1]), gv=ftanh(zg4[2]), ov=hsig(zg4[3]);
  float cc = c0[hoff+u];
  float c2 = fv*cc + iv*gv;
  out[hoff+u] = ov*ftanh(c2);
}

extern "C" void kernel_launch(void* const* d_in, const int* in_sizes, int n_in,
                              void* d_out, int out_size, void* d_ws, size_t ws_size,
                              hipStream_t stream)
{
  const float* x   = (const float*)d_in[0];
  const float* h0  = (const float*)d_in[1];
  const float* c0  = (const float*)d_in[2];
  const float* A   = (const float*)d_in[3];
  const float* ei  = (const float*)d_in[4];
  const float* wg0 = (const float*)d_in[5];
  const float* bg0 = (const float*)d_in[6];
  const float* wg1 = (const float*)d_in[7];
  const float* bg1 = (const float*)d_in[8];
  const float* wr1 = (const float*)d_in[9];
  const float* br1 = (const float*)d_in[10];
  const float* kern  = (const float*)d_in[11];
  const float* kernB = (const float*)d_in[12];
  const float* kernW = (const float*)d_in[13];
  const float* rk    = (const float*)d_in[14];
  const float* rkB   = (const float*)d_in[15];
  const float* rkW   = (const float*)d_in[16];
  const float* bias  = (const float*)d_in[17];
  const float* biasB = (const float*)d_in[18];
  const float* biasW = (const float*)d_in[19];
  float* out = (float*)d_out;
  char* wsb  = (char*)d_ws;

  // ws layout (bytes), total 149.7 MB (< 157.3 MB proven):
  //  [0, 52428800)                        featb (bf16, 102400x256)
  //  [52428800, 94158848)                 weights: WbJ|WbB|WbW|Wc2|Wc1 (41.73 MB)
  //  [94158848, 146587648)   dyn region:  graph temps (ycat|yb; xcat overlays)
  //                                       then h0bJ (joint) then part (split-K)
  //  [146587648, 149733376)               hB (2 MB) | hW (1 MB)
  unsigned short* featb = (unsigned short*)wsb;
  unsigned short* WbJ = (unsigned short*)(wsb + 52428800);
  unsigned short* WbB = WbJ + 524288;
  unsigned short* WbW = WbB + 6815744;
  unsigned short* Wc2 = WbW + 13369344;
  unsigned short* Wc1 = Wc2 + 131072;
  char* dyn = wsb + 94158848;
  unsigned short* ycat = (unsigned short*)dyn;
  unsigned short* xcat = ycat;
  unsigned short* yb   = (unsigned short*)(dyn + 39321600);
  unsigned short* h0bJ = (unsigned short*)dyn;                  // after graph phase
  float* part = (float*)dyn;                                    // after joint
  unsigned short* hB = (unsigned short*)(wsb + 146587648);
  unsigned short* hW = hB + 1048576;

  // ALL weight/h converts in one launch
  kPrep<<<PREP_TOTAL/256, 256, 0, stream>>>(
      kern, rk, kernB, rkB, kernW, rkW, wg1, wr1, wg0, h0,
      WbJ, WbB, WbW, Wc2, Wc1, hB, hW);

  for(int c=0;c<NCH;++c){
    const float* xc = x + (size_t)c*NnC*(Vv*Dd);
    kMix<64,float>          <<<NnC, 192, 0, stream>>>(xc, A, ei, 0, xcat);
    kGC1<<<RCn/128, 512, 0, stream>>>(xcat, Wc1, bg0, A, ei, yb);
    kMix<128,unsigned short><<<NnC, 384, 0, stream>>>(yb, A, ei, 1875, ycat);
    kGC2<<<RCn/128, 512, 0, stream>>>(ycat, yb, Wc2, bg1, br1, A, ei,
                                      featb + (size_t)c*RCn*256);
  }
  // joint h -> bf16 into dyn (graph temps now dead)
  kConvH<0><<<(6553600+255)/256, 256, 0, stream>>>(h0, h0bJ, 6553600);
  // joint: 128-row 8-wave blocks, WT=0 fused epilogue, T1 swizzle (3200 blocks)
  kLSTMm<0,0><<<(N3/128)*4, 512, 0, stream>>>(featb, h0bJ, c0, WbJ, bias, out, 512);
  // body: split-K S=3 (KC=2240), WT=1 64x64 waves, (32*4) x 3
  kLSTMm<1,1><<<dim3((Nn/128)*4,3), 512, 0, stream>>>(featb, hB, nullptr, WbB, nullptr, part, 2240);
  kFin<1><<<Nn, 256, 0, stream>>>(part, c0, biasB, out, 3);
  // whole: split-K S=6 (KC=2176), WT=1 64x64 waves, (16*4) x 6
  kLSTMm<2,1><<<dim3((Bn/128)*4,6), 512, 0, stream>>>(featb, hW, nullptr, WbW, nullptr, part, 2176);
  kFin<2><<<Bn, 256, 0, stream>>>(part, c0, biasW, out, 6);
}